// Round 1
// baseline (12063.873 us; speedup 1.0000x reference)
//
#include <hip/hip_runtime.h>
#include <math.h>

#define TLEN 1024
#define DM   768
#define NH   12
#define HSZ  64
#define DF_  3072
#define NL   12
#define VC   50257

__device__ __forceinline__ float gelu_exact(float x){
  return 0.5f * x * (1.0f + erff(x * 0.70710678118654752f));
}

// ---------------- embedding: h[t,d] = wte[x[t],d] + wpe[t,d] ----------------
__global__ __launch_bounds__(256) void embed_k(const int* __restrict__ x,
    const float* __restrict__ wte, const float* __restrict__ wpe,
    float* __restrict__ h)
{
  int i = blockIdx.x * 256 + threadIdx.x;      // 0 .. TLEN*DM-1
  int t = i / DM, d = i - t * DM;
  h[i] = wte[(size_t)x[t] * DM + d] + wpe[i];
}

// ---------------- layernorm: 1 wave per row, 4 rows/block -------------------
__global__ __launch_bounds__(256) void ln_k(const float* __restrict__ in,
    const float* __restrict__ sc, const float* __restrict__ bi,
    float* __restrict__ out)
{
  int w = threadIdx.x >> 6, lane = threadIdx.x & 63;
  int row = blockIdx.x * 4 + w;
  const float* r = in + (size_t)row * DM;
  float v[12];
  float s = 0.f, s2 = 0.f;
  #pragma unroll
  for (int i = 0; i < 12; i++){
    float xv = r[lane + i * 64];
    v[i] = xv; s += xv; s2 += xv * xv;
  }
  #pragma unroll
  for (int off = 32; off; off >>= 1){
    s  += __shfl_xor(s,  off);
    s2 += __shfl_xor(s2, off);
  }
  float mu  = s * (1.0f / DM);
  float var = s2 * (1.0f / DM) - mu * mu;     // biased var, matches jnp.var
  float rs  = rsqrtf(var + 1e-5f);
  float* o = out + (size_t)row * DM;
  #pragma unroll
  for (int i = 0; i < 12; i++){
    int c = lane + i * 64;
    o[c] = (v[i] - mu) * rs * sc[c] + bi[c];
  }
}

// ---------------- generic fp32 GEMM, 64x64 tile, BK=16, 4x4/thread ----------
// MODE 0: QKV  — B is [H][K][64] per-head, C is [H][M][64], bias[nb*64+col]
// MODE 1: MLP1 — C = gelu(A@B + bias)
// MODE 2: MLP2 — C += A@B + bias      (residual)
// MODE 3: LM   — C = A@B, N not multiple of 64 (bounds-guarded)
template<int MODE>
__global__ __launch_bounds__(256) void gemm_k(
    const float* __restrict__ A, const float* __restrict__ B,
    const float* __restrict__ bias, float* __restrict__ C,
    int M, int N, int K)
{
  __shared__ float As[16][65];   // [k][m], padded
  __shared__ float Bs[16][64];   // [k][n]
  int tid = threadIdx.x;
  int tx = tid & 15, ty = tid >> 4;
  int nb = blockIdx.x, mb = blockIdx.y;
  int m0 = mb * 64;

  const float* Bp; float* Cp; int ldb, n0;
  if (MODE == 0){ Bp = B + (size_t)nb * K * 64; ldb = 64; n0 = 0;
                  Cp = C + (size_t)nb * M * 64; }
  else          { Bp = B; ldb = N; n0 = nb * 64; Cp = C; }

  int am = tid >> 2;            // 0..63 (row within A tile)
  int ak = (tid & 3) * 4;       // 0,4,8,12
  int bk = tid >> 4;            // 0..15 (row within B tile)
  int bn = (tid & 15) * 4;      // 0..60

  float acc[4][4] = {{0.f}};

  for (int k0 = 0; k0 < K; k0 += 16){
    float4 av = *(const float4*)(A + (size_t)(m0 + am) * K + k0 + ak);
    As[ak+0][am] = av.x; As[ak+1][am] = av.y;
    As[ak+2][am] = av.z; As[ak+3][am] = av.w;
    if (MODE == 3){
      int cb = n0 + bn;
      float4 bv;
      bv.x = (cb+0 < N) ? Bp[(size_t)(k0+bk)*ldb + cb+0] : 0.f;
      bv.y = (cb+1 < N) ? Bp[(size_t)(k0+bk)*ldb + cb+1] : 0.f;
      bv.z = (cb+2 < N) ? Bp[(size_t)(k0+bk)*ldb + cb+2] : 0.f;
      bv.w = (cb+3 < N) ? Bp[(size_t)(k0+bk)*ldb + cb+3] : 0.f;
      *(float4*)&Bs[bk][bn] = bv;
    } else {
      *(float4*)&Bs[bk][bn] = *(const float4*)(Bp + (size_t)(k0+bk)*ldb + n0 + bn);
    }
    __syncthreads();
    #pragma unroll
    for (int kk = 0; kk < 16; kk++){
      float a0 = As[kk][ty*4+0], a1 = As[kk][ty*4+1],
            a2 = As[kk][ty*4+2], a3 = As[kk][ty*4+3];
      float b0 = Bs[kk][tx*4+0], b1 = Bs[kk][tx*4+1],
            b2 = Bs[kk][tx*4+2], b3 = Bs[kk][tx*4+3];
      acc[0][0] = fmaf(a0,b0,acc[0][0]); acc[0][1] = fmaf(a0,b1,acc[0][1]);
      acc[0][2] = fmaf(a0,b2,acc[0][2]); acc[0][3] = fmaf(a0,b3,acc[0][3]);
      acc[1][0] = fmaf(a1,b0,acc[1][0]); acc[1][1] = fmaf(a1,b1,acc[1][1]);
      acc[1][2] = fmaf(a1,b2,acc[1][2]); acc[1][3] = fmaf(a1,b3,acc[1][3]);
      acc[2][0] = fmaf(a2,b0,acc[2][0]); acc[2][1] = fmaf(a2,b1,acc[2][1]);
      acc[2][2] = fmaf(a2,b2,acc[2][2]); acc[2][3] = fmaf(a2,b3,acc[2][3]);
      acc[3][0] = fmaf(a3,b0,acc[3][0]); acc[3][1] = fmaf(a3,b1,acc[3][1]);
      acc[3][2] = fmaf(a3,b2,acc[3][2]); acc[3][3] = fmaf(a3,b3,acc[3][3]);
    }
    __syncthreads();
  }

  #pragma unroll
  for (int i = 0; i < 4; i++){
    int m = m0 + ty*4 + i;
    #pragma unroll
    for (int j = 0; j < 4; j++){
      int nl = tx*4 + j;
      int n  = n0 + nl;
      float vv = acc[i][j];
      if (MODE == 0){
        vv += bias[nb*64 + nl];
        Cp[(size_t)m*64 + nl] = vv;
      } else if (MODE == 1){
        vv += bias[n];
        Cp[(size_t)m*N + n] = gelu_exact(vv);
      } else if (MODE == 2){
        vv += bias[n];
        Cp[(size_t)m*N + n] += vv;
      } else {
        if (n < N) Cp[(size_t)m*N + n] = vv;
      }
    }
  }
}

// ---------------- fused causal attention: 1 wave per (head, t) row ----------
// scores NOT scaled by 1/sqrt(HS) (matches reference). Adds result into h.
__global__ __launch_bounds__(256) void attn_k(const float* __restrict__ q,
    const float* __restrict__ k, const float* __restrict__ v,
    float* __restrict__ h)
{
  int w = threadIdx.x >> 6, lane = threadIdx.x & 63;
  int r = blockIdx.x * 4 + w;          // 0 .. NH*TLEN-1
  int head = r >> 10, t = r & 1023;
  const float4* qr = (const float4*)(q + ((size_t)(head << 10) + t) * HSZ);
  const float*  kh = k + (size_t)(head << 10) * HSZ;
  const float*  vh = v + (size_t)(head << 10) * HSZ;

  float4 qv[16];
  #pragma unroll
  for (int i = 0; i < 16; i++) qv[i] = qr[i];

  float o[64];
  #pragma unroll
  for (int i = 0; i < 64; i++) o[i] = 0.f;
  float m = -3.0e38f, lsum = 0.f;

  for (int s0 = 0; s0 <= t; s0 += 64){
    int s = s0 + lane;
    bool act = (s <= t);
    int sidx = act ? s : t;            // clamp so loads stay in-bounds
    float sc = -3.0e38f;
    {
      const float4* kr = (const float4*)(kh + (size_t)sidx * HSZ);
      float a0=0.f, a1=0.f, a2=0.f, a3=0.f;
      #pragma unroll
      for (int i = 0; i < 16; i++){
        float4 kk = kr[i];
        a0 = fmaf(qv[i].x, kk.x, a0); a1 = fmaf(qv[i].y, kk.y, a1);
        a2 = fmaf(qv[i].z, kk.z, a2); a3 = fmaf(qv[i].w, kk.w, a3);
      }
      if (act) sc = (a0 + a1) + (a2 + a3);
    }
    float tm = sc;
    #pragma unroll
    for (int off = 32; off; off >>= 1) tm = fmaxf(tm, __shfl_xor(tm, off));
    float mn = fmaxf(m, tm);
    float p = act ? __expf(sc - mn) : 0.f;
    float corr = __expf(m - mn);       // first iter: exp(-huge) = 0
    float ps = p;
    #pragma unroll
    for (int off = 32; off; off >>= 1) ps += __shfl_xor(ps, off);
    lsum = lsum * corr + ps;
    m = mn;
    const float4* vr = (const float4*)(vh + (size_t)sidx * HSZ);
    #pragma unroll
    for (int i = 0; i < 16; i++){
      float4 vv = vr[i];
      o[i*4+0] = fmaf(p, vv.x, o[i*4+0] * corr);
      o[i*4+1] = fmaf(p, vv.y, o[i*4+1] * corr);
      o[i*4+2] = fmaf(p, vv.z, o[i*4+2] * corr);
      o[i*4+3] = fmaf(p, vv.w, o[i*4+3] * corr);
    }
  }

  float inv = 1.0f / lsum;
  float outv = 0.f;
  #pragma unroll
  for (int e = 0; e < 64; e++){
    float tot = o[e];
    #pragma unroll
    for (int off = 32; off; off >>= 1) tot += __shfl_xor(tot, off);
    if (lane == e) outv = tot;
  }
  h[(size_t)t * DM + head * HSZ + lane] += outv * inv;   // residual add
}

extern "C" void kernel_launch(void* const* d_in, const int* in_sizes, int n_in,
                              void* d_out, int out_size, void* d_ws, size_t ws_size,
                              hipStream_t stream)
{
  const int*   x    = (const int*)  d_in[0];
  const float* wte  = (const float*)d_in[1];
  const float* wpe  = (const float*)d_in[2];
  const float* Wq   = (const float*)d_in[3];
  const float* bq   = (const float*)d_in[4];
  const float* Wk   = (const float*)d_in[5];
  const float* bk   = (const float*)d_in[6];
  const float* Wv   = (const float*)d_in[7];
  const float* bv   = (const float*)d_in[8];
  const float* ln1s = (const float*)d_in[9];
  const float* ln1b = (const float*)d_in[10];
  const float* W1   = (const float*)d_in[11];
  const float* b1   = (const float*)d_in[12];
  const float* W2   = (const float*)d_in[13];
  const float* b2   = (const float*)d_in[14];
  const float* ln2s = (const float*)d_in[15];
  const float* ln2b = (const float*)d_in[16];
  const float* lnfs = (const float*)d_in[17];
  const float* lnfb = (const float*)d_in[18];
  const float* Wlm  = (const float*)d_in[19];
  float* out = (float*)d_out;

  float* ws = (float*)d_ws;
  float* h  = ws;
  float* xn = h  + (size_t)TLEN * DM;
  float* qb = xn + (size_t)TLEN * DM;
  float* kb = qb + (size_t)TLEN * DM;
  float* vb = kb + (size_t)TLEN * DM;
  float* mh = vb + (size_t)TLEN * DM;   // [TLEN, DF_]

  embed_k<<<TLEN*DM/256, 256, 0, stream>>>(x, wte, wpe, h);

  for (int l = 0; l < NL; ++l){
    ln_k<<<TLEN/4, 256, 0, stream>>>(h, ln1s + l*DM, ln1b + l*DM, xn);
    size_t wOff = (size_t)l * NH * DM * HSZ;
    gemm_k<0><<<dim3(NH, TLEN/64), 256, 0, stream>>>(xn, Wq + wOff, bq + l*DM, qb, TLEN, 64, DM);
    gemm_k<0><<<dim3(NH, TLEN/64), 256, 0, stream>>>(xn, Wk + wOff, bk + l*DM, kb, TLEN, 64, DM);
    gemm_k<0><<<dim3(NH, TLEN/64), 256, 0, stream>>>(xn, Wv + wOff, bv + l*DM, vb, TLEN, 64, DM);
    attn_k<<<NH*TLEN/4, 256, 0, stream>>>(qb, kb, vb, h);
    ln_k<<<TLEN/4, 256, 0, stream>>>(h, ln2s + l*DM, ln2b + l*DM, xn);
    gemm_k<1><<<dim3(DF_/64, TLEN/64), 256, 0, stream>>>(xn, W1 + (size_t)l*DM*DF_, b1 + l*DF_, mh, TLEN, DF_, DM);
    gemm_k<2><<<dim3(DM/64, TLEN/64), 256, 0, stream>>>(mh, W2 + (size_t)l*DF_*DM, b2 + l*DM, h, TLEN, DM, DF_);
  }

  ln_k<<<TLEN/4, 256, 0, stream>>>(h, lnfs, lnfb, xn);
  gemm_k<3><<<dim3((VC+63)/64, TLEN/64), 256, 0, stream>>>(xn, Wlm, nullptr, out, TLEN, VC, DM);
}

// Round 2
// 8328.093 us; speedup vs baseline: 1.4486x; 1.4486x over previous
//
#include <hip/hip_runtime.h>
#include <math.h>

#define TLEN 1024
#define DM   768
#define NH   12
#define HSZ  64
#define DF_  3072
#define NL   12
#define VC   50257

typedef __attribute__((ext_vector_type(8))) short bf16x8;
typedef __attribute__((ext_vector_type(4))) float f32x4;

__device__ __forceinline__ float gelu_exact(float x){
  return 0.5f * x * (1.0f + erff(x * 0.70710678118654752f));
}
// fp32 -> bf16 bits, round-to-nearest-even (finite inputs)
__device__ __forceinline__ short f2bf(float f){
  union { float f; unsigned u; } x; x.f = f;
  unsigned r = x.u + 0x7fffu + ((x.u >> 16) & 1u);
  return (short)(r >> 16);
}

// ---------------- embedding: h[t,d] = wte[x[t],d] + wpe[t,d] ----------------
__global__ __launch_bounds__(256) void embed_k(const int* __restrict__ x,
    const float* __restrict__ wte, const float* __restrict__ wpe,
    float* __restrict__ h)
{
  int i = blockIdx.x * 256 + threadIdx.x;
  int t = i / DM, d = i - t * DM;
  h[i] = wte[(size_t)x[t] * DM + d] + wpe[i];
}

// ---------------- layernorm: fp32 in (h), bf16 out ------------------------
__global__ __launch_bounds__(256) void ln_k(const float* __restrict__ in,
    const float* __restrict__ sc, const float* __restrict__ bi,
    short* __restrict__ out)
{
  int w = threadIdx.x >> 6, lane = threadIdx.x & 63;
  int row = blockIdx.x * 4 + w;
  const float* r = in + (size_t)row * DM;
  float v[12];
  float s = 0.f, s2 = 0.f;
  #pragma unroll
  for (int i = 0; i < 12; i++){
    float xv = r[lane + i * 64];
    v[i] = xv; s += xv; s2 += xv * xv;
  }
  #pragma unroll
  for (int off = 32; off; off >>= 1){
    s  += __shfl_xor(s,  off);
    s2 += __shfl_xor(s2, off);
  }
  float mu  = s * (1.0f / DM);
  float var = s2 * (1.0f / DM) - mu * mu;
  float rs  = rsqrtf(var + 1e-5f);
  short* o = out + (size_t)row * DM;
  #pragma unroll
  for (int i = 0; i < 12; i++){
    int c = lane + i * 64;
    o[c] = f2bf((v[i] - mu) * rs * sc[c] + bi[c]);
  }
}

// ---------------- bf16 MFMA GEMM: 64x64 tile, BK=32, 4 waves ----------------
// A: [M][K] bf16 (short). B: [K][ldb] fp32, cast to bf16 while staging.
// MODE 0: QKV  — blockIdx.y = head; B per-head [K][64]; C fp32 [head][M][64] +bias
// MODE 1: MLP1 — C = bf16(gelu(acc + bias)), ldc = N
// MODE 2: MLP2 — C(fp32) += acc + bias (residual)
// MODE 3: LM   — C(fp32) = acc, N-guarded, scalar B loads (ldb odd)
#define LDST 40   // LDS row stride in elements (80B: 16B-aligned, bank-friendly)
template<int MODE>
__global__ __launch_bounds__(256) void mgemm_k(
    const short* __restrict__ A, const float* __restrict__ B,
    const float* __restrict__ bias, void* __restrict__ Cv,
    int M, int N, int K, int ldb)
{
  __shared__ short As[64 * LDST];
  __shared__ short Bs[64 * LDST];
  int tid = threadIdx.x;
  int mb = blockIdx.x, nb = blockIdx.y;
  int m0 = mb * 64;

  int wid = tid >> 6, lane = tid & 63;
  int wr = wid >> 1, wc = wid & 1;       // 32x32 quadrant per wave
  int l15 = lane & 15, l4 = lane >> 4;

  const float* Bp; const float* bias_p; int n0;
  if (MODE == 0){ Bp = B + (size_t)nb * K * 64; bias_p = bias + nb * 64; n0 = 0; }
  else          { Bp = B; bias_p = bias; n0 = nb * 64; }

  // staging maps
  int a_r = tid >> 2, a_k = (tid & 3) * 8;       // A: 16B (8 bf16) per thread
  int b_k = tid >> 3, b_n = (tid & 7) * 8;       // B: 8 fp32 per thread
  int g   = tid & 7;                              // n-group (for bank rotation)

  f32x4 acc[2][2] = {};

  for (int k0 = 0; k0 < K; k0 += 32){
    bf16x8 av = *(const bf16x8*)(A + (size_t)(m0 + a_r) * K + k0 + a_k);
    float bf[8];
    if (MODE == 3){
      const float* bp = Bp + (size_t)(k0 + b_k) * ldb + n0 + b_n;
      #pragma unroll
      for (int u = 0; u < 8; u++){
        int c = n0 + b_n + u;
        bf[u] = (c < N) ? bp[u] : 0.f;
      }
    } else {
      const float4* bp = (const float4*)(Bp + (size_t)(k0 + b_k) * ldb + n0 + b_n);
      float4 v0 = bp[0], v1 = bp[1];
      bf[0]=v0.x; bf[1]=v0.y; bf[2]=v0.z; bf[3]=v0.w;
      bf[4]=v1.x; bf[5]=v1.y; bf[6]=v1.z; bf[7]=v1.w;
    }
    __syncthreads();                       // prior iteration's frag reads done
    *(bf16x8*)(&As[a_r * LDST + a_k]) = av;
    #pragma unroll
    for (int uu = 0; uu < 8; uu++){        // rotate write order: breaks 16-way bank clash
      int u = (uu + g) & 7;
      Bs[(b_n + u) * LDST + b_k] = f2bf(bf[u]);
    }
    __syncthreads();
    #pragma unroll
    for (int i = 0; i < 2; i++){
      bf16x8 af = *(const bf16x8*)(&As[(wr*32 + i*16 + l15) * LDST + l4*8]);
      #pragma unroll
      for (int j = 0; j < 2; j++){
        bf16x8 bfr = *(const bf16x8*)(&Bs[(wc*32 + j*16 + l15) * LDST + l4*8]);
        acc[i][j] = __builtin_amdgcn_mfma_f32_16x16x32_bf16(af, bfr, acc[i][j], 0, 0, 0);
      }
    }
  }

  #pragma unroll
  for (int i = 0; i < 2; i++){
    #pragma unroll
    for (int j = 0; j < 2; j++){
      #pragma unroll
      for (int r = 0; r < 4; r++){
        int row = m0 + wr*32 + i*16 + l4*4 + r;
        int lcol = wc*32 + j*16 + l15;      // col within 64-tile
        int col = n0 + lcol;
        float v = acc[i][j][r];
        if (MODE == 0){
          float* Cp = (float*)Cv + (size_t)nb * M * 64;
          Cp[(size_t)row * 64 + lcol] = v + bias_p[lcol];
        } else if (MODE == 1){
          ((short*)Cv)[(size_t)row * N + col] = f2bf(gelu_exact(v + bias_p[col]));
        } else if (MODE == 2){
          ((float*)Cv)[(size_t)row * N + col] += v + bias_p[col];
        } else {
          if (col < N) ((float*)Cv)[(size_t)row * N + col] = v;
        }
      }
    }
  }
}

// ---------------- fused causal attention (fp32), 1 wave per (head,t) --------
__global__ __launch_bounds__(256) void attn_k(const float* __restrict__ q,
    const float* __restrict__ k, const float* __restrict__ v,
    float* __restrict__ h)
{
  int w = threadIdx.x >> 6, lane = threadIdx.x & 63;
  int r = blockIdx.x * 4 + w;
  int head = r >> 10, t = r & 1023;
  const float4* qr = (const float4*)(q + ((size_t)(head << 10) + t) * HSZ);
  const float*  kh = k + (size_t)(head << 10) * HSZ;
  const float*  vh = v + (size_t)(head << 10) * HSZ;

  float4 qv[16];
  #pragma unroll
  for (int i = 0; i < 16; i++) qv[i] = qr[i];

  float o[64];
  #pragma unroll
  for (int i = 0; i < 64; i++) o[i] = 0.f;
  float m = -3.0e38f, lsum = 0.f;

  for (int s0 = 0; s0 <= t; s0 += 64){
    int s = s0 + lane;
    bool act = (s <= t);
    int sidx = act ? s : t;
    float sc = -3.0e38f;
    {
      const float4* kr = (const float4*)(kh + (size_t)sidx * HSZ);
      float a0=0.f, a1=0.f, a2=0.f, a3=0.f;
      #pragma unroll
      for (int i = 0; i < 16; i++){
        float4 kk = kr[i];
        a0 = fmaf(qv[i].x, kk.x, a0); a1 = fmaf(qv[i].y, kk.y, a1);
        a2 = fmaf(qv[i].z, kk.z, a2); a3 = fmaf(qv[i].w, kk.w, a3);
      }
      if (act) sc = (a0 + a1) + (a2 + a3);
    }
    float tm = sc;
    #pragma unroll
    for (int off = 32; off; off >>= 1) tm = fmaxf(tm, __shfl_xor(tm, off));
    float mn = fmaxf(m, tm);
    float p = act ? __expf(sc - mn) : 0.f;
    float corr = __expf(m - mn);
    float ps = p;
    #pragma unroll
    for (int off = 32; off; off >>= 1) ps += __shfl_xor(ps, off);
    lsum = lsum * corr + ps;
    m = mn;
    const float4* vr = (const float4*)(vh + (size_t)sidx * HSZ);
    #pragma unroll
    for (int i = 0; i < 16; i++){
      float4 vv = vr[i];
      o[i*4+0] = fmaf(p, vv.x, o[i*4+0] * corr);
      o[i*4+1] = fmaf(p, vv.y, o[i*4+1] * corr);
      o[i*4+2] = fmaf(p, vv.z, o[i*4+2] * corr);
      o[i*4+3] = fmaf(p, vv.w, o[i*4+3] * corr);
    }
  }

  float inv = 1.0f / lsum;
  float outv = 0.f;
  #pragma unroll
  for (int e = 0; e < 64; e++){
    float tot = o[e];
    #pragma unroll
    for (int off = 32; off; off >>= 1) tot += __shfl_xor(tot, off);
    if (lane == e) outv = tot;
  }
  h[(size_t)t * DM + head * HSZ + lane] += outv * inv;
}

extern "C" void kernel_launch(void* const* d_in, const int* in_sizes, int n_in,
                              void* d_out, int out_size, void* d_ws, size_t ws_size,
                              hipStream_t stream)
{
  const int*   x    = (const int*)  d_in[0];
  const float* wte  = (const float*)d_in[1];
  const float* wpe  = (const float*)d_in[2];
  const float* Wq   = (const float*)d_in[3];
  const float* bq   = (const float*)d_in[4];
  const float* Wk   = (const float*)d_in[5];
  const float* bk   = (const float*)d_in[6];
  const float* Wv   = (const float*)d_in[7];
  const float* bv   = (const float*)d_in[8];
  const float* ln1s = (const float*)d_in[9];
  const float* ln1b = (const float*)d_in[10];
  const float* W1   = (const float*)d_in[11];
  const float* b1   = (const float*)d_in[12];
  const float* W2   = (const float*)d_in[13];
  const float* b2   = (const float*)d_in[14];
  const float* ln2s = (const float*)d_in[15];
  const float* ln2b = (const float*)d_in[16];
  const float* lnfs = (const float*)d_in[17];
  const float* lnfb = (const float*)d_in[18];
  const float* Wlm  = (const float*)d_in[19];
  float* out = (float*)d_out;

  char* ws = (char*)d_ws;
  float* h    = (float*)ws;                          ws += (size_t)TLEN*DM*4;
  float* qb   = (float*)ws;                          ws += (size_t)TLEN*DM*4;
  float* kb   = (float*)ws;                          ws += (size_t)TLEN*DM*4;
  float* vb   = (float*)ws;                          ws += (size_t)TLEN*DM*4;
  short* xnb  = (short*)ws;                          ws += (size_t)TLEN*DM*2;
  short* mhb  = (short*)ws;                          /* TLEN*DF_*2 */

  embed_k<<<TLEN*DM/256, 256, 0, stream>>>(x, wte, wpe, h);

  for (int l = 0; l < NL; ++l){
    ln_k<<<TLEN/4, 256, 0, stream>>>(h, ln1s + l*DM, ln1b + l*DM, xnb);
    size_t wOff = (size_t)l * NH * DM * HSZ;
    mgemm_k<0><<<dim3(16, NH), 256, 0, stream>>>(xnb, Wq + wOff, bq + l*DM, qb, TLEN, 64, DM, 64);
    mgemm_k<0><<<dim3(16, NH), 256, 0, stream>>>(xnb, Wk + wOff, bk + l*DM, kb, TLEN, 64, DM, 64);
    mgemm_k<0><<<dim3(16, NH), 256, 0, stream>>>(xnb, Wv + wOff, bv + l*DM, vb, TLEN, 64, DM, 64);
    attn_k<<<NH*TLEN/4, 256, 0, stream>>>(qb, kb, vb, h);
    ln_k<<<TLEN/4, 256, 0, stream>>>(h, ln2s + l*DM, ln2b + l*DM, xnb);
    mgemm_k<1><<<dim3(16, DF_/64), 256, 0, stream>>>(xnb, W1 + (size_t)l*DM*DF_, b1 + l*DF_, mhb, TLEN, DF_, DM, DF_);
    mgemm_k<2><<<dim3(16, DM/64), 256, 0, stream>>>(mhb, W2 + (size_t)l*DF_*DM, b2 + l*DM, h, TLEN, DM, DF_, DM);
  }

  ln_k<<<TLEN/4, 256, 0, stream>>>(h, lnfs, lnfb, xnb);
  mgemm_k<3><<<dim3(16, (VC+63)/64), 256, 0, stream>>>(xnb, Wlm, nullptr, out, TLEN, VC, DM, VC);
}

// Round 3
// 6473.302 us; speedup vs baseline: 1.8636x; 1.2865x over previous
//
#include <hip/hip_runtime.h>
#include <math.h>

#define TLEN 1024
#define DM   768
#define NH   12
#define HSZ  64
#define DF_  3072
#define NL   12
#define VC   50257
#define VCP  50304          // VC padded to 64

typedef __attribute__((ext_vector_type(8))) short bf16x8;
typedef __attribute__((ext_vector_type(4))) float f32x4;

__device__ __forceinline__ float gelu_exact(float x){
  return 0.5f * x * (1.0f + erff(x * 0.70710678118654752f));
}
__device__ __forceinline__ short f2bf(float f){
  union { float f; unsigned u; } x; x.f = f;
  unsigned r = x.u + 0x7fffu + ((x.u >> 16) & 1u);
  return (short)(r >> 16);
}
__device__ __forceinline__ void gl16(const void* g, void* l){
  __builtin_amdgcn_global_load_lds(
      (const __attribute__((address_space(1))) unsigned int*)g,
      (__attribute__((address_space(3))) unsigned int*)l, 16, 0, 0);
}

// ---------------- embedding ----------------
__global__ __launch_bounds__(256) void embed_k(const int* __restrict__ x,
    const float* __restrict__ wte, const float* __restrict__ wpe,
    float* __restrict__ h)
{
  int i = blockIdx.x * 256 + threadIdx.x;
  int t = i / DM, d = i - t * DM;
  h[i] = wte[(size_t)x[t] * DM + d] + wpe[i];
}

// ---------------- layernorm: fp32 in, bf16 out ----------------
__global__ __launch_bounds__(256) void ln_k(const float* __restrict__ in,
    const float* __restrict__ sc, const float* __restrict__ bi,
    short* __restrict__ out)
{
  int w = threadIdx.x >> 6, lane = threadIdx.x & 63;
  int row = blockIdx.x * 4 + w;
  const float* r = in + (size_t)row * DM;
  float v[12];
  float s = 0.f, s2 = 0.f;
  #pragma unroll
  for (int i = 0; i < 12; i++){
    float xv = r[lane + i * 64];
    v[i] = xv; s += xv; s2 += xv * xv;
  }
  #pragma unroll
  for (int off = 32; off; off >>= 1){
    s  += __shfl_xor(s,  off);
    s2 += __shfl_xor(s2, off);
  }
  float mu  = s * (1.0f / DM);
  float var = s2 * (1.0f / DM) - mu * mu;
  float rs  = rsqrtf(var + 1e-5f);
  short* o = out + (size_t)row * DM;
  #pragma unroll
  for (int i = 0; i < 12; i++){
    int c = lane + i * 64;
    o[c] = f2bf((v[i] - mu) * rs * sc[c] + bi[c]);
  }
}

// ---------------- transpose-cast: W [K][N] f32 -> WT [Nt*64][K] bf16 --------
__global__ __launch_bounds__(256) void tc_k(const float* __restrict__ in,
    short* __restrict__ out, int K, int N, int ntiles, int per_mat,
    size_t in_stride, size_t out_stride)
{
  __shared__ short sh[64][65];
  int b = blockIdx.x;
  int l = b / per_mat, r = b - l * per_mat;
  int nt = r % ntiles, kt = r / ntiles;
  const float* ip = in + (size_t)l * in_stride;
  short* op = out + (size_t)l * out_stride;
  int n0 = nt * 64, k0 = kt * 64;
  int tid = threadIdx.x;
  #pragma unroll
  for (int it = 0; it < 16; it++){
    int idx = it * 256 + tid;
    int k = idx >> 6, n = idx & 63;
    float v = (n0 + n < N) ? ip[(size_t)(k0 + k) * N + n0 + n] : 0.f;
    sh[k][n] = f2bf(v);
  }
  __syncthreads();
  #pragma unroll
  for (int it = 0; it < 2; it++){
    int n = it * 32 + (tid >> 3);
    int kc = (tid & 7) * 8;
    bf16x8 v;
    #pragma unroll
    for (int u = 0; u < 8; u++) v[u] = sh[kc + u][n];
    *(bf16x8*)(op + (size_t)(n0 + n) * K + k0 + kc) = v;
  }
}

// ---------------- QKV transpose-cast: [L][H][768][64] x3 -> [L][2304][768] --
__global__ __launch_bounds__(256) void tcqkv_k(const float* __restrict__ Wq,
    const float* __restrict__ Wk, const float* __restrict__ Wv,
    short* __restrict__ out)
{
  __shared__ short sh[64][65];
  int b = blockIdx.x;            // L*H*12
  int l = b / 144; int r = b - l * 144;
  int h = r / 12, kt = r - h * 12;
  int tid = threadIdx.x;
  for (int p = 0; p < 3; p++){
    const float* ip = (p == 0 ? Wq : p == 1 ? Wk : Wv)
                      + ((size_t)(l * NH + h) * DM + kt * 64) * 64;
    if (p) __syncthreads();
    #pragma unroll
    for (int it = 0; it < 16; it++){
      int idx = it * 256 + tid;
      int k = idx >> 6, e = idx & 63;
      sh[k][e] = f2bf(ip[(size_t)k * 64 + e]);
    }
    __syncthreads();
    short* op = out + (size_t)l * 2304 * DM + (size_t)(p * DM + h * 64) * DM;
    #pragma unroll
    for (int it = 0; it < 2; it++){
      int e = it * 32 + (tid >> 3);
      int kc = (tid & 7) * 8;
      bf16x8 v;
      #pragma unroll
      for (int u = 0; u < 8; u++) v[u] = sh[kc + u][e];
      *(bf16x8*)(op + (size_t)e * DM + kt * 64 + kc) = v;
    }
  }
}

// ---------------- MFMA GEMM, B^T bf16, global_load_lds + XOR swizzle --------
// BM = FI*32, BN = 128, BK = 64; 256 threads, 4 waves, wave = (BM/2)x64.
// MODE 0: QKV fused (N=2304) -> q/k/v fp32 [head][T][64] + bias
// MODE 1: MLP1 -> bf16 gelu(acc+bias), ldc=3072
// MODE 2: MLP2 split-K (z) -> atomicAdd into h fp32 (+bias on z==0)
// MODE 3: LM   -> fp32 out, col<VC guard
template<int MODE, int FI>
__global__ __launch_bounds__(256) void mg_k(
    const short* __restrict__ A, const short* __restrict__ Bt,
    const float* __restrict__ b0, const float* __restrict__ b1,
    const float* __restrict__ b2,
    void* __restrict__ C0, void* __restrict__ C1, void* __restrict__ C2)
{
  constexpr int BM  = FI * 32;
  constexpr int LDA = (MODE == 2) ? DF_ : DM;
  __shared__ __align__(16) short As[BM * 64];
  __shared__ __align__(16) short Bs[128 * 64];

  int tid = threadIdx.x;
  int wid = tid >> 6, lane = tid & 63;
  int l15 = lane & 15, l4 = lane >> 4;
  int wr = wid >> 1, wc = wid & 1;
  int m0 = blockIdx.x * BM, n0 = blockIdx.y * 128;
  int kbeg = (MODE == 2) ? blockIdx.z * (DF_ / 2) : 0;
  int kend = (MODE == 2) ? kbeg + DF_ / 2 : LDA;

  f32x4 acc[FI][4] = {};
  int wbase = (tid & ~63) * 16;

  for (int k0 = kbeg; k0 < kend; k0 += 64){
    #pragma unroll
    for (int ia = 0; ia < FI; ia++){
      int d = ia * 256 + tid;
      int row = d >> 3, gs = (d & 7) ^ (row & 7);
      gl16(A + (size_t)(m0 + row) * LDA + k0 + gs * 8,
           (char*)As + ia * 4096 + wbase);
    }
    #pragma unroll
    for (int ib = 0; ib < 4; ib++){
      int d = ib * 256 + tid;
      int row = d >> 3, gs = (d & 7) ^ (row & 7);
      gl16(Bt + (size_t)(n0 + row) * LDA + k0 + gs * 8,
           (char*)Bs + ib * 4096 + wbase);
    }
    __syncthreads();
    #pragma unroll
    for (int kk = 0; kk < 2; kk++){
      bf16x8 af[FI], bfr[4];
      #pragma unroll
      for (int i = 0; i < FI; i++){
        int row = wr * (FI * 16) + i * 16 + l15;
        af[i] = *(const bf16x8*)((char*)As + row * 128
                                 + (((kk * 4 + l4) ^ (row & 7)) * 16));
      }
      #pragma unroll
      for (int j = 0; j < 4; j++){
        int row = wc * 64 + j * 16 + l15;
        bfr[j] = *(const bf16x8*)((char*)Bs + row * 128
                                  + (((kk * 4 + l4) ^ (row & 7)) * 16));
      }
      #pragma unroll
      for (int i = 0; i < FI; i++)
        #pragma unroll
        for (int j = 0; j < 4; j++)
          acc[i][j] = __builtin_amdgcn_mfma_f32_16x16x32_bf16(af[i], bfr[j], acc[i][j], 0, 0, 0);
    }
    __syncthreads();
  }

  #pragma unroll
  for (int i = 0; i < FI; i++){
    int rowb = m0 + wr * (FI * 16) + i * 16 + l4 * 4;
    #pragma unroll
    for (int j = 0; j < 4; j++){
      int col = n0 + wc * 64 + j * 16 + l15;
      #pragma unroll
      for (int r = 0; r < 4; r++){
        float v = acc[i][j][r];
        int rw = rowb + r;
        if (MODE == 0){
          int p = col / DM, within = col - p * DM;
          const float* bp = (p == 0) ? b0 : (p == 1) ? b1 : b2;
          float* dst = (float*)((p == 0) ? C0 : (p == 1) ? C1 : C2);
          int hd = within >> 6, e = within & 63;
          dst[((size_t)hd * TLEN + rw) * 64 + e] = v + bp[within];
        } else if (MODE == 1){
          ((short*)C0)[(size_t)rw * DF_ + col] = f2bf(gelu_exact(v + b0[col]));
        } else if (MODE == 2){
          float add = v + (blockIdx.z == 0 ? b0[col] : 0.f);
          atomicAdd((float*)C0 + (size_t)rw * DM + col, add);
        } else {
          if (col < VC) ((float*)C0)[(size_t)rw * VC + col] = v;
        }
      }
    }
  }
}

// ---------------- fused causal attention (fp32), 1 wave per (head,t) --------
__global__ __launch_bounds__(256) void attn_k(const float* __restrict__ q,
    const float* __restrict__ k, const float* __restrict__ v,
    float* __restrict__ h)
{
  int w = threadIdx.x >> 6, lane = threadIdx.x & 63;
  int r = blockIdx.x * 4 + w;
  int head = r >> 10, t = r & 1023;
  const float4* qr = (const float4*)(q + ((size_t)(head << 10) + t) * HSZ);
  const float*  kh = k + (size_t)(head << 10) * HSZ;
  const float*  vh = v + (size_t)(head << 10) * HSZ;

  float4 qv[16];
  #pragma unroll
  for (int i = 0; i < 16; i++) qv[i] = qr[i];

  float o[64];
  #pragma unroll
  for (int i = 0; i < 64; i++) o[i] = 0.f;
  float m = -3.0e38f, lsum = 0.f;

  for (int s0 = 0; s0 <= t; s0 += 64){
    int s = s0 + lane;
    bool act = (s <= t);
    int sidx = act ? s : t;
    float sc = -3.0e38f;
    {
      const float4* kr = (const float4*)(kh + (size_t)sidx * HSZ);
      float a0=0.f, a1=0.f, a2=0.f, a3=0.f;
      #pragma unroll
      for (int i = 0; i < 16; i++){
        float4 kk = kr[i];
        a0 = fmaf(qv[i].x, kk.x, a0); a1 = fmaf(qv[i].y, kk.y, a1);
        a2 = fmaf(qv[i].z, kk.z, a2); a3 = fmaf(qv[i].w, kk.w, a3);
      }
      if (act) sc = (a0 + a1) + (a2 + a3);
    }
    float tm = sc;
    #pragma unroll
    for (int off = 32; off; off >>= 1) tm = fmaxf(tm, __shfl_xor(tm, off));
    float mn = fmaxf(m, tm);
    float p = act ? __expf(sc - mn) : 0.f;
    float corr = __expf(m - mn);
    float ps = p;
    #pragma unroll
    for (int off = 32; off; off >>= 1) ps += __shfl_xor(ps, off);
    lsum = lsum * corr + ps;
    m = mn;
    const float4* vr = (const float4*)(vh + (size_t)sidx * HSZ);
    #pragma unroll
    for (int i = 0; i < 16; i++){
      float4 vv = vr[i];
      o[i*4+0] = fmaf(p, vv.x, o[i*4+0] * corr);
      o[i*4+1] = fmaf(p, vv.y, o[i*4+1] * corr);
      o[i*4+2] = fmaf(p, vv.z, o[i*4+2] * corr);
      o[i*4+3] = fmaf(p, vv.w, o[i*4+3] * corr);
    }
  }

  float inv = 1.0f / lsum;
  float outv = 0.f;
  #pragma unroll
  for (int e = 0; e < 64; e++){
    float tot = o[e];
    #pragma unroll
    for (int off = 32; off; off >>= 1) tot += __shfl_xor(tot, off);
    if (lane == e) outv = tot;
  }
  h[(size_t)t * DM + head * HSZ + lane] += outv * inv;
}

// ======================= FALLBACK (round-2 path) ============================
#define LDST 40
template<int MODE>
__global__ __launch_bounds__(256) void mgemm_k(
    const short* __restrict__ A, const float* __restrict__ B,
    const float* __restrict__ bias, void* __restrict__ Cv,
    int M, int N, int K, int ldb)
{
  __shared__ short As[64 * LDST];
  __shared__ short Bs[64 * LDST];
  int tid = threadIdx.x;
  int mb = blockIdx.x, nb = blockIdx.y;
  int m0 = mb * 64;
  int wid = tid >> 6, lane = tid & 63;
  int wr = wid >> 1, wc = wid & 1;
  int l15 = lane & 15, l4 = lane >> 4;
  const float* Bp; const float* bias_p; int n0;
  if (MODE == 0){ Bp = B + (size_t)nb * K * 64; bias_p = bias + nb * 64; n0 = 0; }
  else          { Bp = B; bias_p = bias; n0 = nb * 64; }
  int a_r = tid >> 2, a_k = (tid & 3) * 8;
  int b_k = tid >> 3, b_n = (tid & 7) * 8;
  int g   = tid & 7;
  f32x4 acc[2][2] = {};
  for (int k0 = 0; k0 < K; k0 += 32){
    bf16x8 av = *(const bf16x8*)(A + (size_t)(m0 + a_r) * K + k0 + a_k);
    float bf[8];
    if (MODE == 3){
      const float* bp = Bp + (size_t)(k0 + b_k) * ldb + n0 + b_n;
      #pragma unroll
      for (int u = 0; u < 8; u++){
        int c = n0 + b_n + u;
        bf[u] = (c < N) ? bp[u] : 0.f;
      }
    } else {
      const float4* bp = (const float4*)(Bp + (size_t)(k0 + b_k) * ldb + n0 + b_n);
      float4 v0 = bp[0], v1 = bp[1];
      bf[0]=v0.x; bf[1]=v0.y; bf[2]=v0.z; bf[3]=v0.w;
      bf[4]=v1.x; bf[5]=v1.y; bf[6]=v1.z; bf[7]=v1.w;
    }
    __syncthreads();
    *(bf16x8*)(&As[a_r * LDST + a_k]) = av;
    #pragma unroll
    for (int uu = 0; uu < 8; uu++){
      int u = (uu + g) & 7;
      Bs[(b_n + u) * LDST + b_k] = f2bf(bf[u]);
    }
    __syncthreads();
    #pragma unroll
    for (int i = 0; i < 2; i++){
      bf16x8 af = *(const bf16x8*)(&As[(wr*32 + i*16 + l15) * LDST + l4*8]);
      #pragma unroll
      for (int j = 0; j < 2; j++){
        bf16x8 bfr = *(const bf16x8*)(&Bs[(wc*32 + j*16 + l15) * LDST + l4*8]);
        acc[i][j] = __builtin_amdgcn_mfma_f32_16x16x32_bf16(af, bfr, acc[i][j], 0, 0, 0);
      }
    }
  }
  #pragma unroll
  for (int i = 0; i < 2; i++){
    #pragma unroll
    for (int j = 0; j < 2; j++){
      #pragma unroll
      for (int r = 0; r < 4; r++){
        int row = m0 + wr*32 + i*16 + l4*4 + r;
        int lcol = wc*32 + j*16 + l15;
        int col = n0 + lcol;
        float v = acc[i][j][r];
        if (MODE == 0){
          float* Cp = (float*)Cv + (size_t)nb * M * 64;
          Cp[(size_t)row * 64 + lcol] = v + bias_p[lcol];
        } else if (MODE == 1){
          ((short*)Cv)[(size_t)row * N + col] = f2bf(gelu_exact(v + bias_p[col]));
        } else if (MODE == 2){
          ((float*)Cv)[(size_t)row * N + col] += v + bias_p[col];
        } else {
          if (col < N) ((float*)Cv)[(size_t)row * N + col] = v;
        }
      }
    }
  }
}

extern "C" void kernel_launch(void* const* d_in, const int* in_sizes, int n_in,
                              void* d_out, int out_size, void* d_ws, size_t ws_size,
                              hipStream_t stream)
{
  const int*   x    = (const int*)  d_in[0];
  const float* wte  = (const float*)d_in[1];
  const float* wpe  = (const float*)d_in[2];
  const float* Wq   = (const float*)d_in[3];
  const float* bq   = (const float*)d_in[4];
  const float* Wk   = (const float*)d_in[5];
  const float* bk   = (const float*)d_in[6];
  const float* Wv   = (const float*)d_in[7];
  const float* bv   = (const float*)d_in[8];
  const float* ln1s = (const float*)d_in[9];
  const float* ln1b = (const float*)d_in[10];
  const float* W1   = (const float*)d_in[11];
  const float* b1   = (const float*)d_in[12];
  const float* W2   = (const float*)d_in[13];
  const float* b2   = (const float*)d_in[14];
  const float* ln2s = (const float*)d_in[15];
  const float* ln2b = (const float*)d_in[16];
  const float* lnfs = (const float*)d_in[17];
  const float* lnfb = (const float*)d_in[18];
  const float* Wlm  = (const float*)d_in[19];
  float* out = (float*)d_out;

  const size_t SZ_QKVT = (size_t)NL * 2304 * DM * 2;
  const size_t SZ_W1T  = (size_t)NL * DF_ * DM * 2;
  const size_t SZ_W2T  = (size_t)NL * DM * DF_ * 2;
  const size_t SZ_WLMT = (size_t)VCP * DM * 2;
  const size_t SZ_H    = (size_t)TLEN * DM * 4;
  const size_t NEED = SZ_QKVT + SZ_W1T + SZ_W2T + SZ_WLMT + 4 * SZ_H
                    + (size_t)TLEN * DM * 2 + (size_t)TLEN * DF_ * 2;

  if (ws_size >= NEED){
    char* ws = (char*)d_ws;
    short* wqkvT = (short*)ws;  ws += SZ_QKVT;
    short* w1T   = (short*)ws;  ws += SZ_W1T;
    short* w2T   = (short*)ws;  ws += SZ_W2T;
    short* wlmT  = (short*)ws;  ws += SZ_WLMT;
    float* h     = (float*)ws;  ws += SZ_H;
    float* qb    = (float*)ws;  ws += SZ_H;
    float* kb    = (float*)ws;  ws += SZ_H;
    float* vb    = (float*)ws;  ws += SZ_H;
    short* xnb   = (short*)ws;  ws += (size_t)TLEN * DM * 2;
    short* mhb   = (short*)ws;

    tcqkv_k<<<NL*NH*12, 256, 0, stream>>>(Wq, Wk, Wv, wqkvT);
    tc_k<<<NL*48*12, 256, 0, stream>>>(W1, w1T, DM, DF_, 48, 576,
                                       (size_t)DM*DF_, (size_t)DM*DF_);
    tc_k<<<NL*12*48, 256, 0, stream>>>(W2, w2T, DF_, DM, 12, 576,
                                       (size_t)DM*DF_, (size_t)DM*DF_);
    tc_k<<<786*12, 256, 0, stream>>>(Wlm, wlmT, DM, VC, 786, 786*12, 0, 0);

    embed_k<<<TLEN*DM/256, 256, 0, stream>>>(x, wte, wpe, h);

    for (int l = 0; l < NL; ++l){
      ln_k<<<TLEN/4, 256, 0, stream>>>(h, ln1s + l*DM, ln1b + l*DM, xnb);
      mg_k<0,2><<<dim3(16,18), 256, 0, stream>>>(xnb, wqkvT + (size_t)l*2304*DM,
          bq + l*DM, bk + l*DM, bv + l*DM, qb, kb, vb);
      attn_k<<<NH*TLEN/4, 256, 0, stream>>>(qb, kb, vb, h);
      ln_k<<<TLEN/4, 256, 0, stream>>>(h, ln2s + l*DM, ln2b + l*DM, xnb);
      mg_k<1,2><<<dim3(16,24), 256, 0, stream>>>(xnb, w1T + (size_t)l*DF_*DM,
          b1 + l*DF_, nullptr, nullptr, mhb, nullptr, nullptr);
      mg_k<2,2><<<dim3(16,6,2), 256, 0, stream>>>(mhb, w2T + (size_t)l*DM*DF_,
          b2 + l*DM, nullptr, nullptr, h, nullptr, nullptr);
    }

    ln_k<<<TLEN/4, 256, 0, stream>>>(h, lnfs, lnfb, xnb);
    mg_k<3,4><<<dim3(8, VCP/128), 256, 0, stream>>>(xnb, wlmT,
        nullptr, nullptr, nullptr, out, nullptr, nullptr);
  } else {
    // -------- fallback: round-2 path --------
    char* ws = (char*)d_ws;
    float* h    = (float*)ws;  ws += SZ_H;
    float* qb   = (float*)ws;  ws += SZ_H;
    float* kb   = (float*)ws;  ws += SZ_H;
    float* vb   = (float*)ws;  ws += SZ_H;
    short* xnb  = (short*)ws;  ws += (size_t)TLEN*DM*2;
    short* mhb  = (short*)ws;

    embed_k<<<TLEN*DM/256, 256, 0, stream>>>(x, wte, wpe, h);
    for (int l = 0; l < NL; ++l){
      ln_k<<<TLEN/4, 256, 0, stream>>>(h, ln1s + l*DM, ln1b + l*DM, xnb);
      size_t wOff = (size_t)l * NH * DM * HSZ;
      mgemm_k<0><<<dim3(16, NH), 256, 0, stream>>>(xnb, Wq + wOff, bq + l*DM, qb, TLEN, 64, DM, 64);
      mgemm_k<0><<<dim3(16, NH), 256, 0, stream>>>(xnb, Wk + wOff, bk + l*DM, kb, TLEN, 64, DM, 64);
      mgemm_k<0><<<dim3(16, NH), 256, 0, stream>>>(xnb, Wv + wOff, bv + l*DM, vb, TLEN, 64, DM, 64);
      attn_k<<<NH*TLEN/4, 256, 0, stream>>>(qb, kb, vb, h);
      ln_k<<<TLEN/4, 256, 0, stream>>>(h, ln2s + l*DM, ln2b + l*DM, xnb);
      mgemm_k<1><<<dim3(16, DF_/64), 256, 0, stream>>>(xnb, W1 + (size_t)l*DM*DF_, b1 + l*DF_, mhb, TLEN, DF_, DM, DF_);
      mgemm_k<2><<<dim3(16, DM/64), 256, 0, stream>>>(mhb, W2 + (size_t)l*DF_*DM, b2 + l*DM, h, TLEN, DM, DF_, DM);
    }
    ln_k<<<TLEN/4, 256, 0, stream>>>(h, lnfs, lnfb, xnb);
    mgemm_k<3><<<dim3(16, (VC+63)/64), 256, 0, stream>>>(xnb, Wlm, nullptr, out, TLEN, VC, DM, VC);
  }
}

// Round 4
// 1692.965 us; speedup vs baseline: 7.1259x; 3.8236x over previous
//
#include <hip/hip_runtime.h>
#include <math.h>

#define TLEN 1024
#define DM   768
#define NH   12
#define HSZ  64
#define DF_  3072
#define NL   12
#define VC   50257
#define VCP  50304          // VC padded to 64

typedef __attribute__((ext_vector_type(8))) short bf16x8;
typedef __attribute__((ext_vector_type(4))) float f32x4;

__device__ __forceinline__ float gelu_exact(float x){
  return 0.5f * x * (1.0f + erff(x * 0.70710678118654752f));
}
__device__ __forceinline__ short f2bf(float f){
  union { float f; unsigned u; } x; x.f = f;
  unsigned r = x.u + 0x7fffu + ((x.u >> 16) & 1u);
  return (short)(r >> 16);
}
__device__ __forceinline__ void gl16(const void* g, void* l){
  __builtin_amdgcn_global_load_lds(
      (const __attribute__((address_space(1))) unsigned int*)g,
      (__attribute__((address_space(3))) unsigned int*)l, 16, 0, 0);
}

// ---------------- embedding ----------------
__global__ __launch_bounds__(256) void embed_k(const int* __restrict__ x,
    const float* __restrict__ wte, const float* __restrict__ wpe,
    float* __restrict__ h)
{
  int i = blockIdx.x * 256 + threadIdx.x;
  int t = i / DM, d = i - t * DM;
  h[i] = wte[(size_t)x[t] * DM + d] + wpe[i];
}

// ---------------- layernorm: fp32 in, bf16 out ----------------
__global__ __launch_bounds__(256) void ln_k(const float* __restrict__ in,
    const float* __restrict__ sc, const float* __restrict__ bi,
    short* __restrict__ out)
{
  int w = threadIdx.x >> 6, lane = threadIdx.x & 63;
  int row = blockIdx.x * 4 + w;
  const float* r = in + (size_t)row * DM;
  float v[12];
  float s = 0.f, s2 = 0.f;
  #pragma unroll
  for (int i = 0; i < 12; i++){
    float xv = r[lane + i * 64];
    v[i] = xv; s += xv; s2 += xv * xv;
  }
  #pragma unroll
  for (int off = 32; off; off >>= 1){
    s  += __shfl_xor(s,  off);
    s2 += __shfl_xor(s2, off);
  }
  float mu  = s * (1.0f / DM);
  float var = s2 * (1.0f / DM) - mu * mu;
  float rs  = rsqrtf(var + 1e-5f);
  short* o = out + (size_t)row * DM;
  #pragma unroll
  for (int i = 0; i < 12; i++){
    int c = lane + i * 64;
    o[c] = f2bf((v[i] - mu) * rs * sc[c] + bi[c]);
  }
}

// ---------------- transpose-cast: W [K][N] f32 -> WT [Nt*64][K] bf16 --------
__global__ __launch_bounds__(256) void tc_k(const float* __restrict__ in,
    short* __restrict__ out, int K, int N, int ntiles, int per_mat,
    size_t in_stride, size_t out_stride)
{
  __shared__ short sh[64][65];
  int b = blockIdx.x;
  int l = b / per_mat, r = b - l * per_mat;
  int nt = r % ntiles, kt = r / ntiles;
  const float* ip = in + (size_t)l * in_stride;
  short* op = out + (size_t)l * out_stride;
  int n0 = nt * 64, k0 = kt * 64;
  int tid = threadIdx.x;
  #pragma unroll
  for (int it = 0; it < 16; it++){
    int idx = it * 256 + tid;
    int k = idx >> 6, n = idx & 63;
    float v = (n0 + n < N) ? ip[(size_t)(k0 + k) * N + n0 + n] : 0.f;
    sh[k][n] = f2bf(v);
  }
  __syncthreads();
  #pragma unroll
  for (int it = 0; it < 2; it++){
    int n = it * 32 + (tid >> 3);
    int kc = (tid & 7) * 8;
    bf16x8 v;
    #pragma unroll
    for (int u = 0; u < 8; u++) v[u] = sh[kc + u][n];
    *(bf16x8*)(op + (size_t)(n0 + n) * K + k0 + kc) = v;
  }
}

// ---------------- QKV transpose-cast: [L][H][768][64] x3 -> [L][2304][768] --
__global__ __launch_bounds__(256) void tcqkv_k(const float* __restrict__ Wq,
    const float* __restrict__ Wk, const float* __restrict__ Wv,
    short* __restrict__ out)
{
  __shared__ short sh[64][65];
  int b = blockIdx.x;            // L*H*12
  int l = b / 144; int r = b - l * 144;
  int h = r / 12, kt = r - h * 12;
  int tid = threadIdx.x;
  for (int p = 0; p < 3; p++){
    const float* ip = (p == 0 ? Wq : p == 1 ? Wk : Wv)
                      + ((size_t)(l * NH + h) * DM + kt * 64) * 64;
    if (p) __syncthreads();
    #pragma unroll
    for (int it = 0; it < 16; it++){
      int idx = it * 256 + tid;
      int k = idx >> 6, e = idx & 63;
      sh[k][e] = f2bf(ip[(size_t)k * 64 + e]);
    }
    __syncthreads();
    short* op = out + (size_t)l * 2304 * DM + (size_t)(p * DM + h * 64) * DM;
    #pragma unroll
    for (int it = 0; it < 2; it++){
      int e = it * 32 + (tid >> 3);
      int kc = (tid & 7) * 8;
      bf16x8 v;
      #pragma unroll
      for (int u = 0; u < 8; u++) v[u] = sh[kc + u][e];
      *(bf16x8*)(op + (size_t)e * DM + kt * 64 + kc) = v;
    }
  }
}

// ---------------- MFMA GEMM, B^T bf16, global_load_lds + XOR swizzle --------
// BM = FI*32, BN = 128, BK = 64; 256 threads, 4 waves.
// MODE 0: QKV fused (N=2304) -> q,k bf16 [head][T][64]; v bf16 TRANSPOSED
//         vt[head][64][T]; + bias
// MODE 1: MLP1 -> bf16 gelu(acc+bias), ldc=3072
// MODE 2: MLP2 split-K (z) -> atomicAdd into h fp32 (+bias on z==0)
// MODE 3: LM   -> fp32 out, col<VC guard
template<int MODE, int FI>
__global__ __launch_bounds__(256) void mg_k(
    const short* __restrict__ A, const short* __restrict__ Bt,
    const float* __restrict__ b0, const float* __restrict__ b1,
    const float* __restrict__ b2,
    void* __restrict__ C0, void* __restrict__ C1, void* __restrict__ C2)
{
  constexpr int BM  = FI * 32;
  constexpr int LDA = (MODE == 2) ? DF_ : DM;
  __shared__ __align__(16) short As[BM * 64];
  __shared__ __align__(16) short Bs[128 * 64];

  int tid = threadIdx.x;
  int wid = tid >> 6, lane = tid & 63;
  int l15 = lane & 15, l4 = lane >> 4;
  int wr = wid >> 1, wc = wid & 1;
  int m0 = blockIdx.x * BM, n0 = blockIdx.y * 128;
  int kbeg = (MODE == 2) ? blockIdx.z * (DF_ / 2) : 0;
  int kend = (MODE == 2) ? kbeg + DF_ / 2 : LDA;

  f32x4 acc[FI][4] = {};
  int wbase = (tid & ~63) * 16;

  for (int k0 = kbeg; k0 < kend; k0 += 64){
    #pragma unroll
    for (int ia = 0; ia < FI; ia++){
      int d = ia * 256 + tid;
      int row = d >> 3, gs = (d & 7) ^ (row & 7);
      gl16(A + (size_t)(m0 + row) * LDA + k0 + gs * 8,
           (char*)As + ia * 4096 + wbase);
    }
    #pragma unroll
    for (int ib = 0; ib < 4; ib++){
      int d = ib * 256 + tid;
      int row = d >> 3, gs = (d & 7) ^ (row & 7);
      gl16(Bt + (size_t)(n0 + row) * LDA + k0 + gs * 8,
           (char*)Bs + ib * 4096 + wbase);
    }
    __syncthreads();
    #pragma unroll
    for (int kk = 0; kk < 2; kk++){
      bf16x8 af[FI], bfr[4];
      #pragma unroll
      for (int i = 0; i < FI; i++){
        int row = wr * (FI * 16) + i * 16 + l15;
        af[i] = *(const bf16x8*)((char*)As + row * 128
                                 + (((kk * 4 + l4) ^ (row & 7)) * 16));
      }
      #pragma unroll
      for (int j = 0; j < 4; j++){
        int row = wc * 64 + j * 16 + l15;
        bfr[j] = *(const bf16x8*)((char*)Bs + row * 128
                                  + (((kk * 4 + l4) ^ (row & 7)) * 16));
      }
      #pragma unroll
      for (int i = 0; i < FI; i++)
        #pragma unroll
        for (int j = 0; j < 4; j++)
          acc[i][j] = __builtin_amdgcn_mfma_f32_16x16x32_bf16(af[i], bfr[j], acc[i][j], 0, 0, 0);
    }
    __syncthreads();
  }

  #pragma unroll
  for (int i = 0; i < FI; i++){
    int rowb = m0 + wr * (FI * 16) + i * 16 + l4 * 4;
    #pragma unroll
    for (int j = 0; j < 4; j++){
      int col = n0 + wc * 64 + j * 16 + l15;
      if (MODE == 0){
        int p = col / DM, within = col - p * DM;
        const float* bp = (p == 0) ? b0 : (p == 1) ? b1 : b2;
        float bb = bp[within];
        int hd = within >> 6, e = within & 63;
        if (p < 2){
          short* dst = (short*)((p == 0) ? C0 : C1);
          #pragma unroll
          for (int r = 0; r < 4; r++)
            dst[((size_t)hd * TLEN + rowb + r) * 64 + e] = f2bf(acc[i][j][r] + bb);
        } else {
          short4 pk;
          pk.x = f2bf(acc[i][j][0] + bb); pk.y = f2bf(acc[i][j][1] + bb);
          pk.z = f2bf(acc[i][j][2] + bb); pk.w = f2bf(acc[i][j][3] + bb);
          *(short4*)((short*)C2 + ((size_t)hd * 64 + e) * TLEN + rowb) = pk;
        }
      } else if (MODE == 1){
        #pragma unroll
        for (int r = 0; r < 4; r++)
          ((short*)C0)[(size_t)(rowb + r) * DF_ + col] =
              f2bf(gelu_exact(acc[i][j][r] + b0[col]));
      } else if (MODE == 2){
        #pragma unroll
        for (int r = 0; r < 4; r++){
          float add = acc[i][j][r] + (blockIdx.z == 0 ? b0[col] : 0.f);
          atomicAdd((float*)C0 + (size_t)(rowb + r) * DM + col, add);
        }
      } else {
        if (col < VC){
          #pragma unroll
          for (int r = 0; r < 4; r++)
            ((float*)C0)[(size_t)(rowb + r) * VC + col] = acc[i][j][r];
        }
      }
    }
  }
}

// ---------------- MFMA flash attention -------------------------------------
// q,k: bf16 [head][T][64]; vt: bf16 [head][64][T]. Adds into h (fp32).
// 192 blocks x 4 waves; wave owns 16 q-rows (qb = qt*64 + wid*16).
// Scores NOT scaled by 1/sqrt(HS) (matches reference).
__global__ __launch_bounds__(256) void attn_k(const short* __restrict__ q,
    const short* __restrict__ k, const short* __restrict__ vt,
    float* __restrict__ h)
{
  __shared__ short P_lds[4][16][72];
  int tid = threadIdx.x;
  int wid = tid >> 6, lane = tid & 63;
  int l15 = lane & 15, l4 = lane >> 4;
  int head = blockIdx.x >> 4, qt = blockIdx.x & 15;
  int qb = qt * 64 + wid * 16;

  const short* qh = q  + (size_t)head * TLEN * 64;
  const short* kh = k  + (size_t)head * TLEN * 64;
  const short* vh = vt + (size_t)head * 64 * TLEN;

  bf16x8 qf[2];
  qf[0] = *(const bf16x8*)(qh + (size_t)(qb + l15) * 64 + l4 * 8);
  qf[1] = *(const bf16x8*)(qh + (size_t)(qb + l15) * 64 + 32 + l4 * 8);

  f32x4 O[4] = {};
  float mrow[4] = {-3e38f, -3e38f, -3e38f, -3e38f};
  float lrow[4] = {0.f, 0.f, 0.f, 0.f};

  for (int kv0 = 0; kv0 <= qb + 15; kv0 += 64){
    // ---- S = Q K^T  (64 kv cols) ----
    f32x4 S[4] = {};
    #pragma unroll
    for (int kk = 0; kk < 2; kk++){
      #pragma unroll
      for (int j = 0; j < 4; j++){
        bf16x8 kf = *(const bf16x8*)(kh + (size_t)(kv0 + j*16 + l15) * 64
                                     + kk*32 + l4*8);
        S[j] = __builtin_amdgcn_mfma_f32_16x16x32_bf16(qf[kk], kf, S[j], 0, 0, 0);
      }
    }
    // ---- causal mask (only near the diagonal) ----
    if (kv0 + 63 > qb){
      #pragma unroll
      for (int j = 0; j < 4; j++){
        int kvc = kv0 + j*16 + l15;
        #pragma unroll
        for (int r = 0; r < 4; r++)
          if (kvc > qb + l4*4 + r) S[j][r] = -3e38f;
      }
    }
    // ---- online softmax (rows live in (l4, reg); reduce over l15 group) ----
    #pragma unroll
    for (int r = 0; r < 4; r++){
      float mx = fmaxf(fmaxf(S[0][r], S[1][r]), fmaxf(S[2][r], S[3][r]));
      #pragma unroll
      for (int off = 1; off < 16; off <<= 1) mx = fmaxf(mx, __shfl_xor(mx, off));
      float mn = fmaxf(mrow[r], mx);
      float corr = __expf(mrow[r] - mn);
      mrow[r] = mn;
      float sm = 0.f;
      #pragma unroll
      for (int j = 0; j < 4; j++){
        float p = __expf(S[j][r] - mn);
        S[j][r] = p; sm += p;
      }
      #pragma unroll
      for (int off = 1; off < 16; off <<= 1) sm += __shfl_xor(sm, off);
      lrow[r] = lrow[r] * corr + sm;
      #pragma unroll
      for (int j = 0; j < 4; j++) O[j][r] *= corr;
    }
    // ---- P (acc layout) -> bf16 A-frag layout via per-wave LDS ----
    #pragma unroll
    for (int j = 0; j < 4; j++)
      #pragma unroll
      for (int r = 0; r < 4; r++)
        P_lds[wid][l4*4 + r][j*16 + l15] = f2bf(S[j][r]);
    // ---- O += P V ----
    #pragma unroll
    for (int kk = 0; kk < 2; kk++){
      bf16x8 pa = *(const bf16x8*)(&P_lds[wid][l15][kk*32 + l4*8]);
      #pragma unroll
      for (int jd = 0; jd < 4; jd++){
        bf16x8 vf = *(const bf16x8*)(vh + (size_t)(jd*16 + l15) * TLEN
                                     + kv0 + kk*32 + l4*8);
        O[jd] = __builtin_amdgcn_mfma_f32_16x16x32_bf16(pa, vf, O[jd], 0, 0, 0);
      }
    }
  }

  #pragma unroll
  for (int r = 0; r < 4; r++){
    float inv = 1.0f / lrow[r];
    int t = qb + l4*4 + r;
    #pragma unroll
    for (int jd = 0; jd < 4; jd++){
      int d = head * 64 + jd*16 + l15;
      h[(size_t)t * DM + d] += O[jd][r] * inv;
    }
  }
}

extern "C" void kernel_launch(void* const* d_in, const int* in_sizes, int n_in,
                              void* d_out, int out_size, void* d_ws, size_t ws_size,
                              hipStream_t stream)
{
  const int*   x    = (const int*)  d_in[0];
  const float* wte  = (const float*)d_in[1];
  const float* wpe  = (const float*)d_in[2];
  const float* Wq   = (const float*)d_in[3];
  const float* bq   = (const float*)d_in[4];
  const float* Wk   = (const float*)d_in[5];
  const float* bk   = (const float*)d_in[6];
  const float* Wv   = (const float*)d_in[7];
  const float* bv   = (const float*)d_in[8];
  const float* ln1s = (const float*)d_in[9];
  const float* ln1b = (const float*)d_in[10];
  const float* W1   = (const float*)d_in[11];
  const float* b1   = (const float*)d_in[12];
  const float* W2   = (const float*)d_in[13];
  const float* b2   = (const float*)d_in[14];
  const float* ln2s = (const float*)d_in[15];
  const float* ln2b = (const float*)d_in[16];
  const float* lnfs = (const float*)d_in[17];
  const float* lnfb = (const float*)d_in[18];
  const float* Wlm  = (const float*)d_in[19];
  float* out = (float*)d_out;

  const size_t SZ_QKVT = (size_t)NL * 2304 * DM * 2;
  const size_t SZ_W1T  = (size_t)NL * DF_ * DM * 2;
  const size_t SZ_W2T  = (size_t)NL * DM * DF_ * 2;
  const size_t SZ_WLMT = (size_t)VCP * DM * 2;
  const size_t SZ_H    = (size_t)TLEN * DM * 4;
  const size_t SZ_BF   = (size_t)TLEN * DM * 2;

  char* ws = (char*)d_ws;
  short* wqkvT = (short*)ws;  ws += SZ_QKVT;
  short* w1T   = (short*)ws;  ws += SZ_W1T;
  short* w2T   = (short*)ws;  ws += SZ_W2T;
  short* wlmT  = (short*)ws;  ws += SZ_WLMT;
  float* h     = (float*)ws;  ws += SZ_H;
  short* qb    = (short*)ws;  ws += SZ_BF;
  short* kb    = (short*)ws;  ws += SZ_BF;
  short* vtb   = (short*)ws;  ws += SZ_BF;
  short* xnb   = (short*)ws;  ws += SZ_BF;
  short* mhb   = (short*)ws;

  tcqkv_k<<<NL*NH*12, 256, 0, stream>>>(Wq, Wk, Wv, wqkvT);
  tc_k<<<NL*48*12, 256, 0, stream>>>(W1, w1T, DM, DF_, 48, 576,
                                     (size_t)DM*DF_, (size_t)DM*DF_);
  tc_k<<<NL*12*48, 256, 0, stream>>>(W2, w2T, DF_, DM, 12, 576,
                                     (size_t)DM*DF_, (size_t)DM*DF_);
  tc_k<<<786*12, 256, 0, stream>>>(Wlm, wlmT, DM, VC, 786, 786*12, 0, 0);

  embed_k<<<TLEN*DM/256, 256, 0, stream>>>(x, wte, wpe, h);

  for (int l = 0; l < NL; ++l){
    ln_k<<<TLEN/4, 256, 0, stream>>>(h, ln1s + l*DM, ln1b + l*DM, xnb);
    mg_k<0,2><<<dim3(16,18), 256, 0, stream>>>(xnb, wqkvT + (size_t)l*2304*DM,
        bq + l*DM, bk + l*DM, bv + l*DM, qb, kb, vtb);
    attn_k<<<NH*16, 256, 0, stream>>>(qb, kb, vtb, h);
    ln_k<<<TLEN/4, 256, 0, stream>>>(h, ln2s + l*DM, ln2b + l*DM, xnb);
    mg_k<1,2><<<dim3(16,24), 256, 0, stream>>>(xnb, w1T + (size_t)l*DF_*DM,
        b1 + l*DF_, nullptr, nullptr, mhb, nullptr, nullptr);
    mg_k<2,2><<<dim3(16,6,2), 256, 0, stream>>>(mhb, w2T + (size_t)l*DM*DF_,
        b2 + l*DM, nullptr, nullptr, h, nullptr, nullptr);
  }

  ln_k<<<TLEN/4, 256, 0, stream>>>(h, lnfs, lnfb, xnb);
  mg_k<3,4><<<dim3(8, VCP/128), 256, 0, stream>>>(xnb, wlmT,
      nullptr, nullptr, nullptr, out, nullptr, nullptr);
}